// Round 4
// baseline (522.497 us; speedup 1.0000x reference)
//
#include <hip/hip_runtime.h>
#include <cstddef>

// Shapes: B=8, NWIN=256, NTOK=64, DIM=192, HEADS=6, d=32, 3C=576
// ws layout (u16 units from base):
//   vT16    [0,        25165824)  bf16 v transposed [(b*192+ch)][win*64+tok]
//   attbuf  [25165824, 50331648)  bf16 softmax@V output [(b*192+ch)][i*64+tok]
//   qg,kg   f32 at u16 offset 50331648 (2 x 393216 f32)
//   Wh [576][192] bf16, Wl [384][192] bf16 (qkv weight hi/lo), Wp [192][192] bf16

#define SCALE 0.17677669529663687f   // 1/sqrt(32)

typedef __attribute__((ext_vector_type(8))) short short8;
typedef __attribute__((ext_vector_type(4))) float f32x4;

__device__ __forceinline__ unsigned short f2bf(float f) {
    unsigned u = __float_as_uint(f);
    u += 0x7fffu + ((u >> 16) & 1u);
    return (unsigned short)(u >> 16);
}
__device__ __forceinline__ float bf2f(unsigned int h) {
    return __uint_as_float(h << 16);
}
__device__ __forceinline__ unsigned pack2(unsigned short a, unsigned short b) {
    return (unsigned)a | ((unsigned)b << 16);
}

// ---------------- qkv weights -> bf16 hi (all 576 rows) + lo (first 384 rows) ----------------
__global__ __launch_bounds__(256) void wsplit_kernel(
    const float* __restrict__ w, unsigned short* __restrict__ Wh,
    unsigned short* __restrict__ Wl)
{
    int idx = blockIdx.x * 256 + threadIdx.x;   // < 110592 = 576*192
    float v = w[idx];
    unsigned short h = f2bf(v);
    Wh[idx] = h;
    if (idx < 73728) Wl[idx] = f2bf(v - bf2f(h));   // rows 0..383 (q,k)
}

// ---------------- proj weights -> bf16 ----------------
__global__ __launch_bounds__(256) void wproj_kernel(
    const float* __restrict__ w, unsigned short* __restrict__ Wp)
{
    int idx = blockIdx.x * 256 + threadIdx.x;   // < 36864
    Wp[idx] = f2bf(w[idx]);
}

// ---------------- Kernel A: fused split + QKV GEMM + grad epilogue ----------------
// v5: m-split N-resident. v3 was latency-bound (VGPR squeezed to 84 -> weight
// prefetch sunk to use; 3 group passes re-read A-frags 3x; 30% occupancy).
// Now 8 waves/block (512 thr): wave (wq = w&3, mh = w>>2) owns all 9 n-tiles
// x its 2 m-tiles -> acc[9][2] = 72 regs, SINGLE kk pass (A-frag reads /6,
// MFMA:ds_read ratio 10.5). Grad epilogue: global-mi 1->2 gy boundary and
// partial sums exchanged between mh pairs via LDS (bnd/ps, 15 KB) + 1 barrier.
// LDS 63 KB -> 2 blocks/CU = 16 waves (50%); launch_bounds(512,4) caps VGPR 128.
// XCD-bijective swizzle: b = bid&7, win = bid>>3 -> consecutive wins on one XCD
// (qg/kg 64-B sectors span 16 wins -> filled in one L2, kills write-amp).
__global__ __launch_bounds__(512, 4) void qkv_fused_kernel(
    const float* __restrict__ x, const unsigned short* __restrict__ Wh,
    const unsigned short* __restrict__ Wl, const float* __restrict__ bias,
    unsigned short* __restrict__ vT, float* __restrict__ qg, float* __restrict__ kg)
{
    // [kk 6][mi 4][kpart 4][col 16][8 u16] ; frag read addr = kk*2048+mi*512+lane*8
    __shared__ unsigned short As_h[6 * 2048];
    __shared__ unsigned short As_l[6 * 2048];
    __shared__ float bnd[24][2][16][4];   // [s*4+wq][quad-2][col][r]: mh0 acc[s][1]
    __shared__ float ps[24][16];          // [s*4+wq][col]: mh0 grad partial

    const int tid = threadIdx.x;
    const int wave = tid >> 6, lane = tid & 63;
    const int quad = lane >> 4, col = lane & 15;
    const int wq = wave & 3, mh = wave >> 2;
    const int bid = blockIdx.x;
    const int b = bid & 7, win = bid >> 3;     // XCD-bijective (2048 = 8*256)
    const int gw = b * 256 + win;
    const int m0 = gw * 64;

    // ---- prologue: stage x -> LDS hi/lo, full K (each thread: 3 kk chunks) ----
    {
        const int khalf = tid >> 8;            // 0..1 -> kk 0-2 / 3-5
        const int t = tid & 255;
        const int arow = t >> 2;               // 0..63
        const int apart = t & 3;               // 0..3 (8 floats each)
        const float* xp = x + (size_t)(m0 + arow) * 192 + apart * 8 + khalf * 96;
        const int slot = (arow >> 4) * 512 + apart * 128 + (arow & 15) * 8;
        float4 va[3], vb[3];
#pragma unroll
        for (int j = 0; j < 3; ++j) {
            va[j] = *(const float4*)(xp + j * 32);
            vb[j] = *(const float4*)(xp + j * 32 + 4);
        }
#pragma unroll
        for (int j = 0; j < 3; ++j) {
            const int kk = khalf * 3 + j;
            float v[8] = {va[j].x, va[j].y, va[j].z, va[j].w,
                          vb[j].x, vb[j].y, vb[j].z, vb[j].w};
            unsigned short h[8], l[8];
#pragma unroll
            for (int i = 0; i < 8; ++i) {
                h[i] = f2bf(v[i]);
                l[i] = f2bf(v[i] - bf2f(h[i]));
            }
            uint4 H = make_uint4(pack2(h[0], h[1]), pack2(h[2], h[3]),
                                 pack2(h[4], h[5]), pack2(h[6], h[7]));
            uint4 L = make_uint4(pack2(l[0], l[1]), pack2(l[2], l[3]),
                                 pack2(l[4], l[5]), pack2(l[6], l[7]));
            *(uint4*)&As_h[kk * 2048 + slot] = H;
            *(uint4*)&As_l[kk * 2048 + slot] = L;
        }
    }
    __syncthreads();

    // B fragment base: row (wq + s*4)*16 + col, k offset quad*8; s stride 12288 u16
    const unsigned short* wh_base = Wh + (size_t)(wq * 16 + col) * 192 + quad * 8;
    const unsigned short* wl_base = Wl + (size_t)(wq * 16 + col) * 192 + quad * 8;

    f32x4 acc[9][2];
#pragma unroll
    for (int s = 0; s < 9; ++s)
#pragma unroll
        for (int ml = 0; ml < 2; ++ml) {
            f32x4 z = {0.f, 0.f, 0.f, 0.f};
            acc[s][ml] = z;
        }

#pragma unroll
    for (int kk = 0; kk < 6; ++kk) {
        short8 ah[2], al[2];
#pragma unroll
        for (int ml = 0; ml < 2; ++ml) {
            const int mi = mh * 2 + ml;
            ah[ml] = *(const short8*)&As_h[kk * 2048 + mi * 512 + lane * 8];
            al[ml] = *(const short8*)&As_l[kk * 2048 + mi * 512 + lane * 8];
        }
#pragma unroll
        for (int s = 0; s < 9; ++s) {
            uint4 wh4 = *(const uint4*)(wh_base + (size_t)s * 12288 + kk * 32);
            short8 bh = *(const short8*)&wh4;
            if (s < 6) {
                uint4 wl4 = *(const uint4*)(wl_base + (size_t)s * 12288 + kk * 32);
                short8 bl = *(const short8*)&wl4;
#pragma unroll
                for (int ml = 0; ml < 2; ++ml) {
                    acc[s][ml] = __builtin_amdgcn_mfma_f32_16x16x32_bf16(al[ml], bh, acc[s][ml], 0, 0, 0);
                    acc[s][ml] = __builtin_amdgcn_mfma_f32_16x16x32_bf16(ah[ml], bl, acc[s][ml], 0, 0, 0);
                    acc[s][ml] = __builtin_amdgcn_mfma_f32_16x16x32_bf16(ah[ml], bh, acc[s][ml], 0, 0, 0);
                }
            } else {
#pragma unroll
                for (int ml = 0; ml < 2; ++ml)
                    acc[s][ml] = __builtin_amdgcn_mfma_f32_16x16x32_bf16(ah[ml], bh, acc[s][ml], 0, 0, 0);
            }
        }
    }

    // bias (zero-pad boundary grad terms keep the bias; internal diffs cancel it)
#pragma unroll
    for (int s = 0; s < 9; ++s) {
        const float bv = bias[(wq + s * 4) * 16 + col];
#pragma unroll
        for (int ml = 0; ml < 2; ++ml)
#pragma unroll
            for (int r = 0; r < 4; ++r)
                acc[s][ml][r] += bv;
    }

    // ---- v stores (s 6..8): independent of exchange, both mh waves ----
#pragma unroll
    for (int s = 6; s < 9; ++s) {
        const int ch = (wq + s * 4 - 24) * 16 + col;
#pragma unroll
        for (int ml = 0; ml < 2; ++ml) {
            const int tok0 = (mh * 2 + ml) * 16 + quad * 4;
            ushort4 o = make_ushort4(f2bf(acc[s][ml][0]), f2bf(acc[s][ml][1]),
                                     f2bf(acc[s][ml][2]), f2bf(acc[s][ml][3]));
            *(ushort4*)(vT + (size_t)(b * 192 + ch) * 16384 + win * 64 + tok0) = o;
        }
    }

    // ---- grad epilogue: q (s 0..2), k (s 3..5) ----
    // tok = mi*16 + quad*4 + r; x = tok&7, y = tok>>3.
    // gx: r>0 in-reg; r==0 & quad odd -> p3 (shfl 16); else zero-pad.
    // gy: quad>=2 -> yx same tile (shfl 32); quad<2 -> prev tile (ml1: yx of ml0;
    //     ml0: mh0 zero-pad, mh1 needs mh0's acc[s][1] via bnd).
    if (mh == 0) {
#pragma unroll
        for (int s = 0; s < 6; ++s) {
            if (quad >= 2) {
#pragma unroll
                for (int r = 0; r < 4; ++r)
                    bnd[s * 4 + wq][quad - 2][col][r] = acc[s][1][r];
            }
            float yx[2][4], p3[2];
#pragma unroll
            for (int ml = 0; ml < 2; ++ml) {
#pragma unroll
                for (int r = 0; r < 4; ++r)
                    yx[ml][r] = __shfl_xor(acc[s][ml][r], 32);
                p3[ml] = __shfl_xor(acc[s][ml][3], 16);
            }
            float sum = 0.f;
#pragma unroll
            for (int ml = 0; ml < 2; ++ml)
#pragma unroll
                for (int r = 0; r < 4; ++r) {
                    float v = acc[s][ml][r];
                    float gx = (r > 0) ? (v - acc[s][ml][r - 1])
                                       : ((quad & 1) ? (v - p3[ml]) : v);
                    float gy = (quad >= 2) ? (v - yx[ml][r])
                                           : ((ml == 1) ? (v - yx[0][r]) : v);
                    sum += fabsf(gx) + fabsf(gy);
                }
            sum += __shfl_xor(sum, 16);
            sum += __shfl_xor(sum, 32);
            if (lane < 16) ps[s * 4 + wq][col] = sum;
        }
    }
    __syncthreads();
    if (mh == 1) {
#pragma unroll
        for (int s = 0; s < 6; ++s) {
            float yx[2][4], p3[2];
#pragma unroll
            for (int ml = 0; ml < 2; ++ml) {
#pragma unroll
                for (int r = 0; r < 4; ++r)
                    yx[ml][r] = __shfl_xor(acc[s][ml][r], 32);
                p3[ml] = __shfl_xor(acc[s][ml][3], 16);
            }
            float sum = 0.f;
#pragma unroll
            for (int ml = 0; ml < 2; ++ml)
#pragma unroll
                for (int r = 0; r < 4; ++r) {
                    float v = acc[s][ml][r];
                    float gx = (r > 0) ? (v - acc[s][ml][r - 1])
                                       : ((quad & 1) ? (v - p3[ml]) : v);
                    float gy;
                    if (quad >= 2) gy = v - yx[ml][r];
                    else if (ml == 1) gy = v - yx[0][r];
                    else gy = v - bnd[s * 4 + wq][quad][col][r];  // global mi 2, prev tile from mh0
                    sum += fabsf(gx) + fabsf(gy);
                }
            sum += __shfl_xor(sum, 16);
            sum += __shfl_xor(sum, 32);
            const float total = sum + ps[s * 4 + wq][col];
            float* dst = (s < 3) ? qg : kg;
            const int chb = ((s < 3) ? (wq + s * 4) : (wq + (s - 3) * 4)) * 16;
            const float sc = (s < 3) ? SCALE : 1.0f;
            if (lane < 16)
                dst[(size_t)(b * 192 + chb + lane) * 256 + win] = total * sc;
        }
    }
}

// ---------------- Kernel B: MFMA rank-1-score softmax attention ----------------
// grid 1536 (one block per (b,ch)), 256 threads = 4 waves; wave w owns query
// windows i in [w*64, w*64+64). C = E[256x256] @ V[256x64], E built in-register.
__global__ __launch_bounds__(256) void attn_mfma_kernel(
    const unsigned short* __restrict__ vT, const float* __restrict__ qg,
    const float* __restrict__ kg, unsigned short* __restrict__ attbuf)
{
    __shared__ unsigned short Vs[64 * 264];   // [tok 64][j 256], stride 264
    __shared__ float kds[256];
    __shared__ float red[256];

    const int g = blockIdx.x;
    const int tid = threadIdx.x;
    const int wave = tid >> 6, lane = tid & 63;
    const int quad = lane >> 4, col = lane & 15;

    float kv = kg[(size_t)g * 256 + tid];
    red[tid] = kv;
    __syncthreads();
    for (int s = 128; s > 0; s >>= 1) {
        if (tid < s) red[tid] = fmaxf(red[tid], red[tid + s]);
        __syncthreads();
    }
    kds[tid] = kv - red[0];                    // <= 0

    // stage V transposed: Vs[tok][j] <- vT[g][j*64+tok]
    const unsigned short* vb = vT + (size_t)g * 16384;
    {
        const int jr = tid >> 3;               // 0..31
        const int tb = (tid & 7) * 8;          // tok base
#pragma unroll
        for (int it = 0; it < 8; ++it) {
            int j = it * 32 + jr;
            uint4 u = *(const uint4*)(vb + (size_t)j * 64 + tb);
            Vs[(tb + 0) * 264 + j] = (unsigned short)(u.x & 0xffffu);
            Vs[(tb + 1) * 264 + j] = (unsigned short)(u.x >> 16);
            Vs[(tb + 2) * 264 + j] = (unsigned short)(u.y & 0xffffu);
            Vs[(tb + 3) * 264 + j] = (unsigned short)(u.y >> 16);
            Vs[(tb + 4) * 264 + j] = (unsigned short)(u.z & 0xffffu);
            Vs[(tb + 5) * 264 + j] = (unsigned short)(u.z >> 16);
            Vs[(tb + 6) * 264 + j] = (unsigned short)(u.w & 0xffffu);
            Vs[(tb + 7) * 264 + j] = (unsigned short)(u.w >> 16);
        }
    }

    float ai[4];
#pragma unroll
    for (int mi = 0; mi < 4; ++mi)
        ai[mi] = qg[(size_t)g * 256 + wave * 64 + mi * 16 + col];

    __syncthreads();

    f32x4 acc[4][4];
#pragma unroll
    for (int mi = 0; mi < 4; ++mi)
#pragma unroll
        for (int ni = 0; ni < 4; ++ni) {
            f32x4 z = {0.f, 0.f, 0.f, 0.f};
            acc[mi][ni] = z;
        }
    float den[4] = {0.f, 0.f, 0.f, 0.f};

    for (int kt = 0; kt < 8; ++kt) {
        const int k0 = kt * 32;
        float4 ka = *(const float4*)&kds[k0 + quad * 8];
        float4 kb = *(const float4*)&kds[k0 + quad * 8 + 4];
        float kv8[8] = {ka.x, ka.y, ka.z, ka.w, kb.x, kb.y, kb.z, kb.w};

        short8 bfr[4];
#pragma unroll
        for (int ni = 0; ni < 4; ++ni)
            bfr[ni] = *(const short8*)&Vs[(ni * 16 + col) * 264 + k0 + quad * 8];

#pragma unroll
        for (int mi = 0; mi < 4; ++mi) {
            short8 ef;
            float dl = 0.f;
#pragma unroll
            for (int j = 0; j < 8; ++j) {
                float e = __expf(ai[mi] * kv8[j]);
                unsigned short h = f2bf(e);
                ef[j] = (short)h;
                dl += bf2f(h);
            }
            den[mi] += dl;
#pragma unroll
            for (int ni = 0; ni < 4; ++ni)
                acc[mi][ni] = __builtin_amdgcn_mfma_f32_16x16x32_bf16(
                    ef, bfr[ni], acc[mi][ni], 0, 0, 0);
        }
    }

#pragma unroll
    for (int mi = 0; mi < 4; ++mi) {
        den[mi] += __shfl_xor(den[mi], 16);
        den[mi] += __shfl_xor(den[mi], 32);
    }

    unsigned short* ob = attbuf + (size_t)g * 16384;
#pragma unroll
    for (int mi = 0; mi < 4; ++mi) {
        float invr[4];
#pragma unroll
        for (int r = 0; r < 4; ++r)
            invr[r] = 1.0f / __shfl(den[mi], quad * 4 + r);
#pragma unroll
        for (int ni = 0; ni < 4; ++ni)
#pragma unroll
            for (int r = 0; r < 4; ++r) {
                int i = wave * 64 + mi * 16 + quad * 4 + r;
                int tok = ni * 16 + col;
                ob[i * 64 + tok] = f2bf(acc[mi][ni][r] * invr[r]);
            }
    }
}

// ---------------- Kernel C: MFMA proj GEMM (C^T = Wp . attbuf^T) ----------------
__global__ __launch_bounds__(256) void proj_mfma_kernel(
    const unsigned short* __restrict__ attbuf, const unsigned short* __restrict__ Wp,
    const float* __restrict__ bias, float* __restrict__ out)
{
    __shared__ unsigned short Bs[64 * 40];    // [row 64][ch 32], stride 40
    __shared__ float T[32 * 197];             // transpose half-buffer

    const int tid = threadIdx.x;
    const int wave = tid >> 6, lane = tid & 63;
    const int quad = lane >> 4, col = lane & 15;
    const int rowg0 = blockIdx.x * 64;
    const int b = rowg0 >> 14;
    const int rl0 = rowg0 & 16383;
    const unsigned short* ab = attbuf + (size_t)b * 3145728;

    f32x4 acc[3][4];
#pragma unroll
    for (int mi = 0; mi < 3; ++mi)
#pragma unroll
        for (int ni = 0; ni < 4; ++ni) {
            f32x4 z = {0.f, 0.f, 0.f, 0.f};
            acc[mi][ni] = z;
        }

    const int chl = tid >> 3;            // 0..31
    const int rb = (tid & 7) * 8;        // row base

    for (int kt = 0; kt < 6; ++kt) {
        __syncthreads();
        {
            uint4 u = *(const uint4*)(ab + (size_t)(kt * 32 + chl) * 16384 + rl0 + rb);
            Bs[(rb + 0) * 40 + chl] = (unsigned short)(u.x & 0xffffu);
            Bs[(rb + 1) * 40 + chl] = (unsigned short)(u.x >> 16);
            Bs[(rb + 2) * 40 + chl] = (unsigned short)(u.y & 0xffffu);
            Bs[(rb + 3) * 40 + chl] = (unsigned short)(u.y >> 16);
            Bs[(rb + 4) * 40 + chl] = (unsigned short)(u.z & 0xffffu);
            Bs[(rb + 5) * 40 + chl] = (unsigned short)(u.z >> 16);
            Bs[(rb + 6) * 40 + chl] = (unsigned short)(u.w & 0xffffu);
            Bs[(rb + 7) * 40 + chl] = (unsigned short)(u.w >> 16);
        }
        __syncthreads();

        short8 bfr[4], af[3];
#pragma unroll
        for (int ni = 0; ni < 4; ++ni)
            bfr[ni] = *(const short8*)&Bs[(ni * 16 + col) * 40 + quad * 8];
#pragma unroll
        for (int mi = 0; mi < 3; ++mi)
            af[mi] = *(const short8*)(Wp + (size_t)(wave * 48 + mi * 16 + col) * 192
                                      + kt * 32 + quad * 8);
#pragma unroll
        for (int mi = 0; mi < 3; ++mi)
#pragma unroll
            for (int ni = 0; ni < 4; ++ni)
                acc[mi][ni] = __builtin_amdgcn_mfma_f32_16x16x32_bf16(
                    af[mi], bfr[ni], acc[mi][ni], 0, 0, 0);
    }

    float br[3][4];
#pragma unroll
    for (int mi = 0; mi < 3; ++mi)
#pragma unroll
        for (int r = 0; r < 4; ++r)
            br[mi][r] = bias[wave * 48 + mi * 16 + quad * 4 + r];

#pragma unroll
    for (int h = 0; h < 2; ++h) {
        __syncthreads();
#pragma unroll
        for (int nh = 0; nh < 2; ++nh) {
            int ni = h * 2 + nh;
#pragma unroll
            for (int mi = 0; mi < 3; ++mi)
#pragma unroll
                for (int r = 0; r < 4; ++r)
                    T[(nh * 16 + col) * 197 + wave * 48 + mi * 16 + quad * 4 + r] =
                        acc[mi][ni][r] + br[mi][r];
        }
        __syncthreads();
        {
            int row = tid >> 3;              // 0..31
            int ck = (tid & 7) * 24;         // cout chunk
            float* op = out + (size_t)(rowg0 + h * 32 + row) * 192 + ck;
#pragma unroll
            for (int q4 = 0; q4 < 6; ++q4) {
                float4 o = make_float4(T[row * 197 + ck + q4 * 4 + 0],
                                       T[row * 197 + ck + q4 * 4 + 1],
                                       T[row * 197 + ck + q4 * 4 + 2],
                                       T[row * 197 + ck + q4 * 4 + 3]);
                *(float4*)(op + q4 * 4) = o;
            }
        }
    }
}

extern "C" void kernel_launch(void* const* d_in, const int* in_sizes, int n_in,
                              void* d_out, int out_size, void* d_ws, size_t ws_size,
                              hipStream_t stream) {
    const float* x      = (const float*)d_in[0];
    const float* qkv_w  = (const float*)d_in[1];
    const float* qkv_b  = (const float*)d_in[2];
    const float* proj_w = (const float*)d_in[3];
    const float* proj_b = (const float*)d_in[4];
    float* out = (float*)d_out;

    unsigned short* base16 = (unsigned short*)d_ws;
    unsigned short* vT16   = base16;                      // 25165824 u16
    unsigned short* attbuf = base16 + 25165824;           // 25165824 u16
    float* qg = (float*)(base16 + 50331648);              // 393216 f32
    float* kg = qg + 393216;                              // 393216 f32
    unsigned short* Wh = (unsigned short*)(kg + 393216);  // 110592 u16
    unsigned short* Wl = Wh + 110592;                     // 73728 u16
    unsigned short* Wp = Wl + 73728;                      // 36864 u16

    wsplit_kernel<<<432, 256, 0, stream>>>(qkv_w, Wh, Wl);
    wproj_kernel<<<144, 256, 0, stream>>>(proj_w, Wp);
    qkv_fused_kernel<<<2048, 512, 0, stream>>>(x, Wh, Wl, qkv_b, vT16, qg, kg);
    attn_mfma_kernel<<<1536, 256, 0, stream>>>(vT16, qg, kg, attbuf);
    proj_mfma_kernel<<<2048, 256, 0, stream>>>(attbuf, Wp, proj_b, out);
}

// Round 5
// 403.069 us; speedup vs baseline: 1.2963x; 1.2963x over previous
//
#include <hip/hip_runtime.h>
#include <cstddef>

// Shapes: B=8, NWIN=256, NTOK=64, DIM=192, HEADS=6, d=32, 3C=576
// ws layout (u16 units from base):
//   vT16    [0,        25165824)  bf16 v transposed [(b*192+ch)][win*64+tok]
//   attbuf  [25165824, 50331648)  bf16 softmax@V output [(b*192+ch)][i*64+tok]
//   qg,kg   f32 at u16 offset 50331648 (2 x 393216 f32)
//   Wh [576][192] bf16, Wl [384][192] bf16 (qkv weight hi/lo), Wp [192][192] bf16

#define SCALE 0.17677669529663687f   // 1/sqrt(32)

typedef __attribute__((ext_vector_type(8))) short short8;
typedef __attribute__((ext_vector_type(4))) float f32x4;

__device__ __forceinline__ unsigned short f2bf(float f) {
    unsigned u = __float_as_uint(f);
    u += 0x7fffu + ((u >> 16) & 1u);
    return (unsigned short)(u >> 16);
}
__device__ __forceinline__ float bf2f(unsigned int h) {
    return __uint_as_float(h << 16);
}
__device__ __forceinline__ unsigned pack2(unsigned short a, unsigned short b) {
    return (unsigned)a | ((unsigned)b << 16);
}

// ---------------- qkv weights -> bf16 hi (all 576 rows) + lo (first 384 rows) ----------------
__global__ __launch_bounds__(256) void wsplit_kernel(
    const float* __restrict__ w, unsigned short* __restrict__ Wh,
    unsigned short* __restrict__ Wl)
{
    int idx = blockIdx.x * 256 + threadIdx.x;   // < 110592 = 576*192
    float v = w[idx];
    unsigned short h = f2bf(v);
    Wh[idx] = h;
    if (idx < 73728) Wl[idx] = f2bf(v - bf2f(h));   // rows 0..383 (q,k)
}

// ---------------- proj weights -> bf16 ----------------
__global__ __launch_bounds__(256) void wproj_kernel(
    const float* __restrict__ w, unsigned short* __restrict__ Wp)
{
    int idx = blockIdx.x * 256 + threadIdx.x;   // < 36864
    Wp[idx] = f2bf(w[idx]);
}

// ---------------- Kernel A: fused split + QKV GEMM + grad epilogue ----------------
// v6 = v3 structure (best measured: 136us, VGPR 84) with two changes aimed at
// the measured limiter (latency-bound at 3 blocks/CU, LDS-capped):
// 1. Per-chunk double-buffered A staging (16 KB total instead of 48 KB full-K):
//    per group pass, re-read x (L2-hot 49KB tile) chunk-by-chunk with depth-2
//    register prefetch; convert hi/lo per chunk. Bit-identical numerics to v3.
//    LDS 16 KB -> LDS cap 10 blocks; launch_bounds(256,4) -> >=4 blocks/CU
//    (16 waves, ~50% occupancy vs 30%).
// 2. XCD-bijective swizzle: c=bid&7 (XCD), i=bid>>3, b=i&7, win=c*32+(i>>3):
//    each XCD owns a contiguous 32-win range per b, so qg/kg 64-B sectors
//    (16 wins) are produced within one L2 -> kills partial-sector write-amp.
__global__ __launch_bounds__(256, 4) void qkv_fused_kernel(
    const float* __restrict__ x, const unsigned short* __restrict__ Wh,
    const unsigned short* __restrict__ Wl, const float* __restrict__ bias,
    unsigned short* __restrict__ vT, float* __restrict__ qg, float* __restrict__ kg)
{
    // per chunk: [mi 4][kpart 4][col 16][8 u16] = 2048 u16; frag read = mi*512+lane*8
    __shared__ unsigned short Ah[2][2048];
    __shared__ unsigned short Al[2][2048];

    const int tid = threadIdx.x;
    const int wq = tid >> 6, lane = tid & 63;
    const int quad = lane >> 4, col = lane & 15;
    const int bid = blockIdx.x;
    const int xcd = bid & 7;
    const int i2 = bid >> 3;
    const int b = i2 & 7;
    const int win = xcd * 32 + (i2 >> 3);      // bijective: (b,win) covers all 2048
    const int m0 = (b * 256 + win) * 64;

    // staging assignment: thread -> (row = tid>>2, kpart = tid&3 of 8 floats)
    const int arow = tid >> 2;              // 0..63
    const int apart = tid & 3;              // 0..3
    const float* xp = x + (size_t)(m0 + arow) * 192 + apart * 8;
    const int slot = (arow >> 4) * 512 + apart * 128 + (arow & 15) * 8;

    // B fragment base: row (wq + s*4)*16 + col, k offset quad*8; s stride 12288 u16
    const unsigned short* wh_base = Wh + (size_t)(wq * 16 + col) * 192 + quad * 8;
    const unsigned short* wl_base = Wl + (size_t)(wq * 16 + col) * 192 + quad * 8;

    float4 SA[2], SB[2];                    // depth-2 x prefetch (reg sets)
    auto xload = [&](int kk, int s) {
        SA[s] = *(const float4*)(xp + kk * 32);
        SB[s] = *(const float4*)(xp + kk * 32 + 4);
    };
    auto cwrite = [&](int kk, int s) {      // convert set s, write chunk kk
        float v[8] = {SA[s].x, SA[s].y, SA[s].z, SA[s].w,
                      SB[s].x, SB[s].y, SB[s].z, SB[s].w};
        unsigned short h[8], l[8];
#pragma unroll
        for (int i = 0; i < 8; ++i) {
            h[i] = f2bf(v[i]);
            l[i] = f2bf(v[i] - bf2f(h[i]));
        }
        uint4 H = make_uint4(pack2(h[0], h[1]), pack2(h[2], h[3]),
                             pack2(h[4], h[5]), pack2(h[6], h[7]));
        uint4 L = make_uint4(pack2(l[0], l[1]), pack2(l[2], l[3]),
                             pack2(l[4], l[5]), pack2(l[6], l[7]));
        *(uint4*)&Ah[kk & 1][slot] = H;
        *(uint4*)&Al[kk & 1][slot] = L;
    };

#pragma unroll
    for (int g = 0; g < 3; ++g) {              // g=0: q, g=1: k, g=2: v
        const bool qk = (g < 2);

        // ---- group prologue: fill the pipe ----
        xload(0, 0);
        xload(1, 1);
        __syncthreads();                       // prev group's buf reads all done
        cwrite(0, 0);
        xload(2, 0);

        f32x4 acc[3][4];
#pragma unroll
        for (int js = 0; js < 3; ++js)
#pragma unroll
            for (int mi = 0; mi < 4; ++mi) {
                f32x4 z = {0.f, 0.f, 0.f, 0.f};
                acc[js][mi] = z;
            }

        uint4 cbh[3], cbl[3], nbh[3], nbl[3];
#pragma unroll
        for (int js = 0; js < 3; ++js) {
            const int s = g * 3 + js;
            cbh[js] = *(const uint4*)(wh_base + (size_t)s * 12288);
            if (qk) cbl[js] = *(const uint4*)(wl_base + (size_t)s * 12288);
        }
        __syncthreads();                       // chunk0 visible

#pragma unroll
        for (int kk = 0; kk < 6; ++kk) {
            // frag-read chunk kk
            short8 ah[4], al[4];
#pragma unroll
            for (int mi = 0; mi < 4; ++mi) {
                ah[mi] = *(const short8*)&Ah[kk & 1][mi * 512 + lane * 8];
                if (qk) al[mi] = *(const short8*)&Al[kk & 1][mi * 512 + lane * 8];
            }
            // stage chunk kk+1 into the other buffer; prefetch x for kk+3
            if (kk < 5) cwrite(kk + 1, (kk + 1) & 1);
            if (kk < 3) xload(kk + 3, (kk + 1) & 1);
            __syncthreads();

            // weight prefetch for kk+1, MFMA on current
            if (kk < 5) {
#pragma unroll
                for (int js = 0; js < 3; ++js) {
                    const int s = g * 3 + js;
                    nbh[js] = *(const uint4*)(wh_base + (size_t)s * 12288 + (kk + 1) * 32);
                    if (qk) nbl[js] = *(const uint4*)(wl_base + (size_t)s * 12288 + (kk + 1) * 32);
                }
            }
#pragma unroll
            for (int js = 0; js < 3; ++js) {
                short8 bh = *(const short8*)&cbh[js];
                if (qk) {
                    short8 bl = *(const short8*)&cbl[js];
#pragma unroll
                    for (int mi = 0; mi < 4; ++mi) {
                        acc[js][mi] = __builtin_amdgcn_mfma_f32_16x16x32_bf16(al[mi], bh, acc[js][mi], 0, 0, 0);
                        acc[js][mi] = __builtin_amdgcn_mfma_f32_16x16x32_bf16(ah[mi], bl, acc[js][mi], 0, 0, 0);
                        acc[js][mi] = __builtin_amdgcn_mfma_f32_16x16x32_bf16(ah[mi], bh, acc[js][mi], 0, 0, 0);
                    }
                } else {
#pragma unroll
                    for (int mi = 0; mi < 4; ++mi)
                        acc[js][mi] = __builtin_amdgcn_mfma_f32_16x16x32_bf16(ah[mi], bh, acc[js][mi], 0, 0, 0);
                }
            }
#pragma unroll
            for (int js = 0; js < 3; ++js) {
                cbh[js] = nbh[js];
                if (qk) cbl[js] = nbl[js];
            }
        }

        // ---- group epilogue (acc still live, only 12 tiles) ----
        if (g < 2) {
            // q (g=0) / k (g=1): bias, grad magnitude, store to qg/kg
#pragma unroll
            for (int js = 0; js < 3; ++js) {
                const int s = g * 3 + js;
                const int n = wq + s * 4;
                const float bv = bias[n * 16 + col];
#pragma unroll
                for (int mi = 0; mi < 4; ++mi)
#pragma unroll
                    for (int r = 0; r < 4; ++r)
                        acc[js][mi][r] += bv;

                float yx[4][4], p3[4];
#pragma unroll
                for (int mi = 0; mi < 4; ++mi) {
#pragma unroll
                    for (int r = 0; r < 4; ++r)
                        yx[mi][r] = __shfl_xor(acc[js][mi][r], 32);
                    p3[mi] = __shfl_xor(acc[js][mi][3], 16);
                }
                float sum = 0.f;
#pragma unroll
                for (int mi = 0; mi < 4; ++mi)
#pragma unroll
                    for (int r = 0; r < 4; ++r) {
                        float v = acc[js][mi][r];
                        float gx = (r > 0) ? (v - acc[js][mi][r - 1])
                                           : ((quad & 1) ? (v - p3[mi]) : v);
                        float gy = (quad >= 2) ? (v - yx[mi][r])
                                               : ((mi > 0) ? (v - yx[mi - 1][r]) : v);
                        sum += fabsf(gx) + fabsf(gy);
                    }
                sum += __shfl_xor(sum, 16);
                sum += __shfl_xor(sum, 32);
                float* dst = (g == 0) ? qg : kg;
                const int chb = ((g == 0) ? n : n - 12) * 16;
                const float sc = (g == 0) ? SCALE : 1.0f;
                if (lane < 16)
                    dst[(size_t)(b * 192 + chb + lane) * 256 + win] = sum * sc;
            }
        } else {
            // v: bias + bf16 store to vT
#pragma unroll
            for (int js = 0; js < 3; ++js) {
                const int s = 6 + js;
                const int n = wq + s * 4;
                const float bv = bias[n * 16 + col];
                const int ch = (n - 24) * 16 + col;
#pragma unroll
                for (int mi = 0; mi < 4; ++mi) {
                    int tok0 = mi * 16 + quad * 4;
                    ushort4 o = make_ushort4(f2bf(acc[js][mi][0] + bv),
                                             f2bf(acc[js][mi][1] + bv),
                                             f2bf(acc[js][mi][2] + bv),
                                             f2bf(acc[js][mi][3] + bv));
                    *(ushort4*)(vT + (size_t)(b * 192 + ch) * 16384 + win * 64 + tok0) = o;
                }
            }
        }
    }
}

// ---------------- Kernel B: MFMA rank-1-score softmax attention ----------------
// grid 1536 (one block per (b,ch)), 256 threads = 4 waves; wave w owns query
// windows i in [w*64, w*64+64). C = E[256x256] @ V[256x64], E built in-register.
__global__ __launch_bounds__(256) void attn_mfma_kernel(
    const unsigned short* __restrict__ vT, const float* __restrict__ qg,
    const float* __restrict__ kg, unsigned short* __restrict__ attbuf)
{
    __shared__ unsigned short Vs[64 * 264];   // [tok 64][j 256], stride 264
    __shared__ float kds[256];
    __shared__ float red[256];

    const int g = blockIdx.x;
    const int tid = threadIdx.x;
    const int wave = tid >> 6, lane = tid & 63;
    const int quad = lane >> 4, col = lane & 15;

    float kv = kg[(size_t)g * 256 + tid];
    red[tid] = kv;
    __syncthreads();
    for (int s = 128; s > 0; s >>= 1) {
        if (tid < s) red[tid] = fmaxf(red[tid], red[tid + s]);
        __syncthreads();
    }
    kds[tid] = kv - red[0];                    // <= 0

    // stage V transposed: Vs[tok][j] <- vT[g][j*64+tok]
    const unsigned short* vb = vT + (size_t)g * 16384;
    {
        const int jr = tid >> 3;               // 0..31
        const int tb = (tid & 7) * 8;          // tok base
#pragma unroll
        for (int it = 0; it < 8; ++it) {
            int j = it * 32 + jr;
            uint4 u = *(const uint4*)(vb + (size_t)j * 64 + tb);
            Vs[(tb + 0) * 264 + j] = (unsigned short)(u.x & 0xffffu);
            Vs[(tb + 1) * 264 + j] = (unsigned short)(u.x >> 16);
            Vs[(tb + 2) * 264 + j] = (unsigned short)(u.y & 0xffffu);
            Vs[(tb + 3) * 264 + j] = (unsigned short)(u.y >> 16);
            Vs[(tb + 4) * 264 + j] = (unsigned short)(u.z & 0xffffu);
            Vs[(tb + 5) * 264 + j] = (unsigned short)(u.z >> 16);
            Vs[(tb + 6) * 264 + j] = (unsigned short)(u.w & 0xffffu);
            Vs[(tb + 7) * 264 + j] = (unsigned short)(u.w >> 16);
        }
    }

    float ai[4];
#pragma unroll
    for (int mi = 0; mi < 4; ++mi)
        ai[mi] = qg[(size_t)g * 256 + wave * 64 + mi * 16 + col];

    __syncthreads();

    f32x4 acc[4][4];
#pragma unroll
    for (int mi = 0; mi < 4; ++mi)
#pragma unroll
        for (int ni = 0; ni < 4; ++ni) {
            f32x4 z = {0.f, 0.f, 0.f, 0.f};
            acc[mi][ni] = z;
        }
    float den[4] = {0.f, 0.f, 0.f, 0.f};

    for (int kt = 0; kt < 8; ++kt) {
        const int k0 = kt * 32;
        float4 ka = *(const float4*)&kds[k0 + quad * 8];
        float4 kb = *(const float4*)&kds[k0 + quad * 8 + 4];
        float kv8[8] = {ka.x, ka.y, ka.z, ka.w, kb.x, kb.y, kb.z, kb.w};

        short8 bfr[4];
#pragma unroll
        for (int ni = 0; ni < 4; ++ni)
            bfr[ni] = *(const short8*)&Vs[(ni * 16 + col) * 264 + k0 + quad * 8];

#pragma unroll
        for (int mi = 0; mi < 4; ++mi) {
            short8 ef;
            float dl = 0.f;
#pragma unroll
            for (int j = 0; j < 8; ++j) {
                float e = __expf(ai[mi] * kv8[j]);
                unsigned short h = f2bf(e);
                ef[j] = (short)h;
                dl += bf2f(h);
            }
            den[mi] += dl;
#pragma unroll
            for (int ni = 0; ni < 4; ++ni)
                acc[mi][ni] = __builtin_amdgcn_mfma_f32_16x16x32_bf16(
                    ef, bfr[ni], acc[mi][ni], 0, 0, 0);
        }
    }

#pragma unroll
    for (int mi = 0; mi < 4; ++mi) {
        den[mi] += __shfl_xor(den[mi], 16);
        den[mi] += __shfl_xor(den[mi], 32);
    }

    unsigned short* ob = attbuf + (size_t)g * 16384;
#pragma unroll
    for (int mi = 0; mi < 4; ++mi) {
        float invr[4];
#pragma unroll
        for (int r = 0; r < 4; ++r)
            invr[r] = 1.0f / __shfl(den[mi], quad * 4 + r);
#pragma unroll
        for (int ni = 0; ni < 4; ++ni)
#pragma unroll
            for (int r = 0; r < 4; ++r) {
                int i = wave * 64 + mi * 16 + quad * 4 + r;
                int tok = ni * 16 + col;
                ob[i * 64 + tok] = f2bf(acc[mi][ni][r] * invr[r]);
            }
    }
}

// ---------------- Kernel C: MFMA proj GEMM (C^T = Wp . attbuf^T) ----------------
__global__ __launch_bounds__(256) void proj_mfma_kernel(
    const unsigned short* __restrict__ attbuf, const unsigned short* __restrict__ Wp,
    const float* __restrict__ bias, float* __restrict__ out)
{
    __shared__ unsigned short Bs[64 * 40];    // [row 64][ch 32], stride 40
    __shared__ float T[32 * 197];             // transpose half-buffer

    const int tid = threadIdx.x;
    const int wave = tid >> 6, lane = tid & 63;
    const int quad = lane >> 4, col = lane & 15;
    const int rowg0 = blockIdx.x * 64;
    const int b = rowg0 >> 14;
    const int rl0 = rowg0 & 16383;
    const unsigned short* ab = attbuf + (size_t)b * 3145728;

    f32x4 acc[3][4];
#pragma unroll
    for (int mi = 0; mi < 3; ++mi)
#pragma unroll
        for (int ni = 0; ni < 4; ++ni) {
            f32x4 z = {0.f, 0.f, 0.f, 0.f};
            acc[mi][ni] = z;
        }

    const int chl = tid >> 3;            // 0..31
    const int rb = (tid & 7) * 8;        // row base

    for (int kt = 0; kt < 6; ++kt) {
        __syncthreads();
        {
            uint4 u = *(const uint4*)(ab + (size_t)(kt * 32 + chl) * 16384 + rl0 + rb);
            Bs[(rb + 0) * 40 + chl] = (unsigned short)(u.x & 0xffffu);
            Bs[(rb + 1) * 40 + chl] = (unsigned short)(u.x >> 16);
            Bs[(rb + 2) * 40 + chl] = (unsigned short)(u.y & 0xffffu);
            Bs[(rb + 3) * 40 + chl] = (unsigned short)(u.y >> 16);
            Bs[(rb + 4) * 40 + chl] = (unsigned short)(u.z & 0xffffu);
            Bs[(rb + 5) * 40 + chl] = (unsigned short)(u.z >> 16);
            Bs[(rb + 6) * 40 + chl] = (unsigned short)(u.w & 0xffffu);
            Bs[(rb + 7) * 40 + chl] = (unsigned short)(u.w >> 16);
        }
        __syncthreads();

        short8 bfr[4], af[3];
#pragma unroll
        for (int ni = 0; ni < 4; ++ni)
            bfr[ni] = *(const short8*)&Bs[(ni * 16 + col) * 40 + quad * 8];
#pragma unroll
        for (int mi = 0; mi < 3; ++mi)
            af[mi] = *(const short8*)(Wp + (size_t)(wave * 48 + mi * 16 + col) * 192
                                      + kt * 32 + quad * 8);
#pragma unroll
        for (int mi = 0; mi < 3; ++mi)
#pragma unroll
            for (int ni = 0; ni < 4; ++ni)
                acc[mi][ni] = __builtin_amdgcn_mfma_f32_16x16x32_bf16(
                    af[mi], bfr[ni], acc[mi][ni], 0, 0, 0);
    }

    float br[3][4];
#pragma unroll
    for (int mi = 0; mi < 3; ++mi)
#pragma unroll
        for (int r = 0; r < 4; ++r)
            br[mi][r] = bias[wave * 48 + mi * 16 + quad * 4 + r];

#pragma unroll
    for (int h = 0; h < 2; ++h) {
        __syncthreads();
#pragma unroll
        for (int nh = 0; nh < 2; ++nh) {
            int ni = h * 2 + nh;
#pragma unroll
            for (int mi = 0; mi < 3; ++mi)
#pragma unroll
                for (int r = 0; r < 4; ++r)
                    T[(nh * 16 + col) * 197 + wave * 48 + mi * 16 + quad * 4 + r] =
                        acc[mi][ni][r] + br[mi][r];
        }
        __syncthreads();
        {
            int row = tid >> 3;              // 0..31
            int ck = (tid & 7) * 24;         // cout chunk
            float* op = out + (size_t)(rowg0 + h * 32 + row) * 192 + ck;
#pragma unroll
            for (int q4 = 0; q4 < 6; ++q4) {
                float4 o = make_float4(T[row * 197 + ck + q4 * 4 + 0],
                                       T[row * 197 + ck + q4 * 4 + 1],
                                       T[row * 197 + ck + q4 * 4 + 2],
                                       T[row * 197 + ck + q4 * 4 + 3]);
                *(float4*)(op + q4 * 4) = o;
            }
        }
    }
}

extern "C" void kernel_launch(void* const* d_in, const int* in_sizes, int n_in,
                              void* d_out, int out_size, void* d_ws, size_t ws_size,
                              hipStream_t stream) {
    const float* x      = (const float*)d_in[0];
    const float* qkv_w  = (const float*)d_in[1];
    const float* qkv_b  = (const float*)d_in[2];
    const float* proj_w = (const float*)d_in[3];
    const float* proj_b = (const float*)d_in[4];
    float* out = (float*)d_out;

    unsigned short* base16 = (unsigned short*)d_ws;
    unsigned short* vT16   = base16;                      // 25165824 u16
    unsigned short* attbuf = base16 + 25165824;           // 25165824 u16
    float* qg = (float*)(base16 + 50331648);              // 393216 f32
    float* kg = qg + 393216;                              // 393216 f32
    unsigned short* Wh = (unsigned short*)(kg + 393216);  // 110592 u16
    unsigned short* Wl = Wh + 110592;                     // 73728 u16
    unsigned short* Wp = Wl + 73728;                      // 36864 u16

    wsplit_kernel<<<432, 256, 0, stream>>>(qkv_w, Wh, Wl);
    wproj_kernel<<<144, 256, 0, stream>>>(proj_w, Wp);
    qkv_fused_kernel<<<2048, 256, 0, stream>>>(x, Wh, Wl, qkv_b, vT16, qg, kg);
    attn_mfma_kernel<<<1536, 256, 0, stream>>>(vT16, qg, kg, attbuf);
    proj_mfma_kernel<<<2048, 256, 0, stream>>>(attbuf, Wp, proj_b, out);
}

// Round 6
// 383.932 us; speedup vs baseline: 1.3609x; 1.0498x over previous
//
#include <hip/hip_runtime.h>
#include <cstddef>

// Shapes: B=8, NWIN=256, NTOK=64, DIM=192, HEADS=6, d=32, 3C=576
// ws layout (u16 units from base):
//   vT16    [0,        25165824)  bf16 v transposed [(b*192+ch)][win*64+tok]
//   attbuf  [25165824, 50331648)  bf16 softmax@V output [(b*192+ch)][i*64+tok]
//   qg,kg   f32 at u16 offset 50331648 (2 x 393216 f32)
//   Wh [576][192] bf16, Wl [384][192] bf16 (qkv weight hi/lo), Wp [192][192] bf16

#define SCALE 0.17677669529663687f   // 1/sqrt(32)

typedef __attribute__((ext_vector_type(8))) short short8;
typedef __attribute__((ext_vector_type(4))) float f32x4;

__device__ __forceinline__ unsigned short f2bf(float f) {
    unsigned u = __float_as_uint(f);
    u += 0x7fffu + ((u >> 16) & 1u);
    return (unsigned short)(u >> 16);
}
__device__ __forceinline__ float bf2f(unsigned int h) {
    return __uint_as_float(h << 16);
}
__device__ __forceinline__ unsigned pack2(unsigned short a, unsigned short b) {
    return (unsigned)a | ((unsigned)b << 16);
}

// ---------------- qkv weights -> bf16 hi (all 576 rows) + lo (first 384 rows) ----------------
__global__ __launch_bounds__(256) void wsplit_kernel(
    const float* __restrict__ w, unsigned short* __restrict__ Wh,
    unsigned short* __restrict__ Wl)
{
    int idx = blockIdx.x * 256 + threadIdx.x;   // < 110592 = 576*192
    float v = w[idx];
    unsigned short h = f2bf(v);
    Wh[idx] = h;
    if (idx < 73728) Wl[idx] = f2bf(v - bf2f(h));   // rows 0..383 (q,k)
}

// ---------------- proj weights -> bf16 ----------------
__global__ __launch_bounds__(256) void wproj_kernel(
    const float* __restrict__ w, unsigned short* __restrict__ Wp)
{
    int idx = blockIdx.x * 256 + threadIdx.x;   // < 36864
    Wp[idx] = f2bf(w[idx]);
}

// ---------------- Kernel A: fused split + QKV GEMM + grad epilogue ----------------
// v7 = v3's register structure (measured 84 VGPR, no spill) + v6's 16 KB
// per-chunk double-buffered A staging + XCD swizzle.
// LESSON (v5/v6): __launch_bounds__ min-waves=4 (VGPR cap 128) makes the
// allocator collapse to 64 regs + massive scratch spills (FETCH/WRITE +100s
// of MB). This body needs ~90-110 regs -> keep the (256,3) cap (~170) and
// get occupancy from LDS instead: 16 KB -> LDS cap 10 blocks/CU; actual
// occupancy = floor(512/VGPR) blocks = ~5 (vs v3's LDS-capped 3).
// x is re-read per group (3x, L2-mostly); numerics bit-identical to v3.
__global__ __launch_bounds__(256, 3) void qkv_fused_kernel(
    const float* __restrict__ x, const unsigned short* __restrict__ Wh,
    const unsigned short* __restrict__ Wl, const float* __restrict__ bias,
    unsigned short* __restrict__ vT, float* __restrict__ qg, float* __restrict__ kg)
{
    // per chunk: [mi 4][kpart 4][col 16][8 u16] = 2048 u16; frag read = mi*512+lane*8
    __shared__ unsigned short Ah[2][2048];
    __shared__ unsigned short Al[2][2048];

    const int tid = threadIdx.x;
    const int wq = tid >> 6, lane = tid & 63;
    const int quad = lane >> 4, col = lane & 15;
    const int bid = blockIdx.x;
    const int xcd = bid & 7;
    const int i2 = bid >> 3;
    const int b = i2 & 7;
    const int win = xcd * 32 + (i2 >> 3);      // bijective: each XCD owns 32 wins/b
    const int m0 = (b * 256 + win) * 64;

    // staging assignment: thread -> (row = tid>>2, kpart = tid&3 of 8 floats)
    const int arow = tid >> 2;              // 0..63
    const int apart = tid & 3;              // 0..3
    const float* xp = x + (size_t)(m0 + arow) * 192 + apart * 8;
    const int slot = (arow >> 4) * 512 + apart * 128 + (arow & 15) * 8;

    // B fragment base: row (wq + s*4)*16 + col, k offset quad*8; s stride 12288 u16
    const unsigned short* wh_base = Wh + (size_t)(wq * 16 + col) * 192 + quad * 8;
    const unsigned short* wl_base = Wl + (size_t)(wq * 16 + col) * 192 + quad * 8;

    float4 SA, SB;                          // single-set x prefetch
    auto xload = [&](int kk) {
        SA = *(const float4*)(xp + kk * 32);
        SB = *(const float4*)(xp + kk * 32 + 4);
    };
    auto cwrite = [&](int kk) {             // convert current SA/SB, write chunk kk
        float v[8] = {SA.x, SA.y, SA.z, SA.w, SB.x, SB.y, SB.z, SB.w};
        unsigned short h[8], l[8];
#pragma unroll
        for (int i = 0; i < 8; ++i) {
            h[i] = f2bf(v[i]);
            l[i] = f2bf(v[i] - bf2f(h[i]));
        }
        uint4 H = make_uint4(pack2(h[0], h[1]), pack2(h[2], h[3]),
                             pack2(h[4], h[5]), pack2(h[6], h[7]));
        uint4 L = make_uint4(pack2(l[0], l[1]), pack2(l[2], l[3]),
                             pack2(l[4], l[5]), pack2(l[6], l[7]));
        *(uint4*)&Ah[kk & 1][slot] = H;
        *(uint4*)&Al[kk & 1][slot] = L;
    };

#pragma unroll
    for (int g = 0; g < 3; ++g) {              // g=0: q, g=1: k, g=2: v
        const bool qk = (g < 2);

        // ---- group prologue ----
        xload(0);
        __syncthreads();                       // prior reads of buf0 done
        cwrite(0);
        xload(1);

        f32x4 acc[3][4];
#pragma unroll
        for (int js = 0; js < 3; ++js)
#pragma unroll
            for (int mi = 0; mi < 4; ++mi) {
                f32x4 z = {0.f, 0.f, 0.f, 0.f};
                acc[js][mi] = z;
            }

        uint4 cbh[3], cbl[3], nbh[3], nbl[3];
#pragma unroll
        for (int js = 0; js < 3; ++js) {
            const int s = g * 3 + js;
            cbh[js] = *(const uint4*)(wh_base + (size_t)s * 12288);
            if (qk) cbl[js] = *(const uint4*)(wl_base + (size_t)s * 12288);
        }
        __syncthreads();                       // chunk0 visible

#pragma unroll
        for (int kk = 0; kk < 6; ++kk) {
            // frag-read chunk kk (pre-barrier: protects vs next overwrite)
            short8 ah[4], al[4];
#pragma unroll
            for (int mi = 0; mi < 4; ++mi) {
                ah[mi] = *(const short8*)&Ah[kk & 1][mi * 512 + lane * 8];
                if (qk) al[mi] = *(const short8*)&Al[kk & 1][mi * 512 + lane * 8];
            }
            // stage chunk kk+1 (other buffer); prefetch x for kk+2
            if (kk < 5) cwrite(kk + 1);
            if (kk < 4) xload(kk + 2);
            __syncthreads();

            // weight prefetch for kk+1, MFMA on current
            if (kk < 5) {
#pragma unroll
                for (int js = 0; js < 3; ++js) {
                    const int s = g * 3 + js;
                    nbh[js] = *(const uint4*)(wh_base + (size_t)s * 12288 + (kk + 1) * 32);
                    if (qk) nbl[js] = *(const uint4*)(wl_base + (size_t)s * 12288 + (kk + 1) * 32);
                }
            }
#pragma unroll
            for (int js = 0; js < 3; ++js) {
                short8 bh = *(const short8*)&cbh[js];
                if (qk) {
                    short8 bl = *(const short8*)&cbl[js];
#pragma unroll
                    for (int mi = 0; mi < 4; ++mi) {
                        acc[js][mi] = __builtin_amdgcn_mfma_f32_16x16x32_bf16(al[mi], bh, acc[js][mi], 0, 0, 0);
                        acc[js][mi] = __builtin_amdgcn_mfma_f32_16x16x32_bf16(ah[mi], bl, acc[js][mi], 0, 0, 0);
                        acc[js][mi] = __builtin_amdgcn_mfma_f32_16x16x32_bf16(ah[mi], bh, acc[js][mi], 0, 0, 0);
                    }
                } else {
#pragma unroll
                    for (int mi = 0; mi < 4; ++mi)
                        acc[js][mi] = __builtin_amdgcn_mfma_f32_16x16x32_bf16(ah[mi], bh, acc[js][mi], 0, 0, 0);
                }
            }
#pragma unroll
            for (int js = 0; js < 3; ++js) {
                cbh[js] = nbh[js];
                if (qk) cbl[js] = nbl[js];
            }
        }

        // ---- group epilogue (acc still live, only 12 tiles) ----
        if (g < 2) {
            // q (g=0) / k (g=1): bias, grad magnitude, store to qg/kg
#pragma unroll
            for (int js = 0; js < 3; ++js) {
                const int s = g * 3 + js;
                const int n = wq + s * 4;
                const float bv = bias[n * 16 + col];
#pragma unroll
                for (int mi = 0; mi < 4; ++mi)
#pragma unroll
                    for (int r = 0; r < 4; ++r)
                        acc[js][mi][r] += bv;

                float yx[4][4], p3[4];
#pragma unroll
                for (int mi = 0; mi < 4; ++mi) {
#pragma unroll
                    for (int r = 0; r < 4; ++r)
                        yx[mi][r] = __shfl_xor(acc[js][mi][r], 32);
                    p3[mi] = __shfl_xor(acc[js][mi][3], 16);
                }
                float sum = 0.f;
#pragma unroll
                for (int mi = 0; mi < 4; ++mi)
#pragma unroll
                    for (int r = 0; r < 4; ++r) {
                        float v = acc[js][mi][r];
                        float gx = (r > 0) ? (v - acc[js][mi][r - 1])
                                           : ((quad & 1) ? (v - p3[mi]) : v);
                        float gy = (quad >= 2) ? (v - yx[mi][r])
                                               : ((mi > 0) ? (v - yx[mi - 1][r]) : v);
                        sum += fabsf(gx) + fabsf(gy);
                    }
                sum += __shfl_xor(sum, 16);
                sum += __shfl_xor(sum, 32);
                float* dst = (g == 0) ? qg : kg;
                const int chb = ((g == 0) ? n : n - 12) * 16;
                const float sc = (g == 0) ? SCALE : 1.0f;
                if (lane < 16)
                    dst[(size_t)(b * 192 + chb + lane) * 256 + win] = sum * sc;
            }
        } else {
            // v: bias + bf16 store to vT
#pragma unroll
            for (int js = 0; js < 3; ++js) {
                const int s = 6 + js;
                const int n = wq + s * 4;
                const float bv = bias[n * 16 + col];
                const int ch = (n - 24) * 16 + col;
#pragma unroll
                for (int mi = 0; mi < 4; ++mi) {
                    int tok0 = mi * 16 + quad * 4;
                    ushort4 o = make_ushort4(f2bf(acc[js][mi][0] + bv),
                                             f2bf(acc[js][mi][1] + bv),
                                             f2bf(acc[js][mi][2] + bv),
                                             f2bf(acc[js][mi][3] + bv));
                    *(ushort4*)(vT + (size_t)(b * 192 + ch) * 16384 + win * 64 + tok0) = o;
                }
            }
        }
    }
}

// ---------------- Kernel B: MFMA rank-1-score softmax attention ----------------
// grid 1536 (one block per (b,ch)), 256 threads = 4 waves; wave w owns query
// windows i in [w*64, w*64+64). C = E[256x256] @ V[256x64], E built in-register.
__global__ __launch_bounds__(256) void attn_mfma_kernel(
    const unsigned short* __restrict__ vT, const float* __restrict__ qg,
    const float* __restrict__ kg, unsigned short* __restrict__ attbuf)
{
    __shared__ unsigned short Vs[64 * 264];   // [tok 64][j 256], stride 264
    __shared__ float kds[256];
    __shared__ float red[256];

    const int g = blockIdx.x;
    const int tid = threadIdx.x;
    const int wave = tid >> 6, lane = tid & 63;
    const int quad = lane >> 4, col = lane & 15;

    float kv = kg[(size_t)g * 256 + tid];
    red[tid] = kv;
    __syncthreads();
    for (int s = 128; s > 0; s >>= 1) {
        if (tid < s) red[tid] = fmaxf(red[tid], red[tid + s]);
        __syncthreads();
    }
    kds[tid] = kv - red[0];                    // <= 0

    // stage V transposed: Vs[tok][j] <- vT[g][j*64+tok]
    const unsigned short* vb = vT + (size_t)g * 16384;
    {
        const int jr = tid >> 3;               // 0..31
        const int tb = (tid & 7) * 8;          // tok base
#pragma unroll
        for (int it = 0; it < 8; ++it) {
            int j = it * 32 + jr;
            uint4 u = *(const uint4*)(vb + (size_t)j * 64 + tb);
            Vs[(tb + 0) * 264 + j] = (unsigned short)(u.x & 0xffffu);
            Vs[(tb + 1) * 264 + j] = (unsigned short)(u.x >> 16);
            Vs[(tb + 2) * 264 + j] = (unsigned short)(u.y & 0xffffu);
            Vs[(tb + 3) * 264 + j] = (unsigned short)(u.y >> 16);
            Vs[(tb + 4) * 264 + j] = (unsigned short)(u.z & 0xffffu);
            Vs[(tb + 5) * 264 + j] = (unsigned short)(u.z >> 16);
            Vs[(tb + 6) * 264 + j] = (unsigned short)(u.w & 0xffffu);
            Vs[(tb + 7) * 264 + j] = (unsigned short)(u.w >> 16);
        }
    }

    float ai[4];
#pragma unroll
    for (int mi = 0; mi < 4; ++mi)
        ai[mi] = qg[(size_t)g * 256 + wave * 64 + mi * 16 + col];

    __syncthreads();

    f32x4 acc[4][4];
#pragma unroll
    for (int mi = 0; mi < 4; ++mi)
#pragma unroll
        for (int ni = 0; ni < 4; ++ni) {
            f32x4 z = {0.f, 0.f, 0.f, 0.f};
            acc[mi][ni] = z;
        }
    float den[4] = {0.f, 0.f, 0.f, 0.f};

    for (int kt = 0; kt < 8; ++kt) {
        const int k0 = kt * 32;
        float4 ka = *(const float4*)&kds[k0 + quad * 8];
        float4 kb = *(const float4*)&kds[k0 + quad * 8 + 4];
        float kv8[8] = {ka.x, ka.y, ka.z, ka.w, kb.x, kb.y, kb.z, kb.w};

        short8 bfr[4];
#pragma unroll
        for (int ni = 0; ni < 4; ++ni)
            bfr[ni] = *(const short8*)&Vs[(ni * 16 + col) * 264 + k0 + quad * 8];

#pragma unroll
        for (int mi = 0; mi < 4; ++mi) {
            short8 ef;
            float dl = 0.f;
#pragma unroll
            for (int j = 0; j < 8; ++j) {
                float e = __expf(ai[mi] * kv8[j]);
                unsigned short h = f2bf(e);
                ef[j] = (short)h;
                dl += bf2f(h);
            }
            den[mi] += dl;
#pragma unroll
            for (int ni = 0; ni < 4; ++ni)
                acc[mi][ni] = __builtin_amdgcn_mfma_f32_16x16x32_bf16(
                    ef, bfr[ni], acc[mi][ni], 0, 0, 0);
        }
    }

#pragma unroll
    for (int mi = 0; mi < 4; ++mi) {
        den[mi] += __shfl_xor(den[mi], 16);
        den[mi] += __shfl_xor(den[mi], 32);
    }

    unsigned short* ob = attbuf + (size_t)g * 16384;
#pragma unroll
    for (int mi = 0; mi < 4; ++mi) {
        float invr[4];
#pragma unroll
        for (int r = 0; r < 4; ++r)
            invr[r] = 1.0f / __shfl(den[mi], quad * 4 + r);
#pragma unroll
        for (int ni = 0; ni < 4; ++ni)
#pragma unroll
            for (int r = 0; r < 4; ++r) {
                int i = wave * 64 + mi * 16 + quad * 4 + r;
                int tok = ni * 16 + col;
                ob[i * 64 + tok] = f2bf(acc[mi][ni][r] * invr[r]);
            }
    }
}

// ---------------- Kernel C: MFMA proj GEMM (C^T = Wp . attbuf^T) ----------------
__global__ __launch_bounds__(256) void proj_mfma_kernel(
    const unsigned short* __restrict__ attbuf, const unsigned short* __restrict__ Wp,
    const float* __restrict__ bias, float* __restrict__ out)
{
    __shared__ unsigned short Bs[64 * 40];    // [row 64][ch 32], stride 40
    __shared__ float T[32 * 197];             // transpose half-buffer

    const int tid = threadIdx.x;
    const int wave = tid >> 6, lane = tid & 63;
    const int quad = lane >> 4, col = lane & 15;
    const int rowg0 = blockIdx.x * 64;
    const int b = rowg0 >> 14;
    const int rl0 = rowg0 & 16383;
    const unsigned short* ab = attbuf + (size_t)b * 3145728;

    f32x4 acc[3][4];
#pragma unroll
    for (int mi = 0; mi < 3; ++mi)
#pragma unroll
        for (int ni = 0; ni < 4; ++ni) {
            f32x4 z = {0.f, 0.f, 0.f, 0.f};
            acc[mi][ni] = z;
        }

    const int chl = tid >> 3;            // 0..31
    const int rb = (tid & 7) * 8;        // row base

    for (int kt = 0; kt < 6; ++kt) {
        __syncthreads();
        {
            uint4 u = *(const uint4*)(ab + (size_t)(kt * 32 + chl) * 16384 + rl0 + rb);
            Bs[(rb + 0) * 40 + chl] = (unsigned short)(u.x & 0xffffu);
            Bs[(rb + 1) * 40 + chl] = (unsigned short)(u.x >> 16);
            Bs[(rb + 2) * 40 + chl] = (unsigned short)(u.y & 0xffffu);
            Bs[(rb + 3) * 40 + chl] = (unsigned short)(u.y >> 16);
            Bs[(rb + 4) * 40 + chl] = (unsigned short)(u.z & 0xffffu);
            Bs[(rb + 5) * 40 + chl] = (unsigned short)(u.z >> 16);
            Bs[(rb + 6) * 40 + chl] = (unsigned short)(u.w & 0xffffu);
            Bs[(rb + 7) * 40 + chl] = (unsigned short)(u.w >> 16);
        }
        __syncthreads();

        short8 bfr[4], af[3];
#pragma unroll
        for (int ni = 0; ni < 4; ++ni)
            bfr[ni] = *(const short8*)&Bs[(ni * 16 + col) * 40 + quad * 8];
#pragma unroll
        for (int mi = 0; mi < 3; ++mi)
            af[mi] = *(const short8*)(Wp + (size_t)(wave * 48 + mi * 16 + col) * 192
                                      + kt * 32 + quad * 8);
#pragma unroll
        for (int mi = 0; mi < 3; ++mi)
#pragma unroll
            for (int ni = 0; ni < 4; ++ni)
                acc[mi][ni] = __builtin_amdgcn_mfma_f32_16x16x32_bf16(
                    af[mi], bfr[ni], acc[mi][ni], 0, 0, 0);
    }

    float br[3][4];
#pragma unroll
    for (int mi = 0; mi < 3; ++mi)
#pragma unroll
        for (int r = 0; r < 4; ++r)
            br[mi][r] = bias[wave * 48 + mi * 16 + quad * 4 + r];

#pragma unroll
    for (int h = 0; h < 2; ++h) {
        __syncthreads();
#pragma unroll
        for (int nh = 0; nh < 2; ++nh) {
            int ni = h * 2 + nh;
#pragma unroll
            for (int mi = 0; mi < 3; ++mi)
#pragma unroll
                for (int r = 0; r < 4; ++r)
                    T[(nh * 16 + col) * 197 + wave * 48 + mi * 16 + quad * 4 + r] =
                        acc[mi][ni][r] + br[mi][r];
        }
        __syncthreads();
        {
            int row = tid >> 3;              // 0..31
            int ck = (tid & 7) * 24;         // cout chunk
            float* op = out + (size_t)(rowg0 + h * 32 + row) * 192 + ck;
#pragma unroll
            for (int q4 = 0; q4 < 6; ++q4) {
                float4 o = make_float4(T[row * 197 + ck + q4 * 4 + 0],
                                       T[row * 197 + ck + q4 * 4 + 1],
                                       T[row * 197 + ck + q4 * 4 + 2],
                                       T[row * 197 + ck + q4 * 4 + 3]);
                *(float4*)(op + q4 * 4) = o;
            }
        }
    }
}

extern "C" void kernel_launch(void* const* d_in, const int* in_sizes, int n_in,
                              void* d_out, int out_size, void* d_ws, size_t ws_size,
                              hipStream_t stream) {
    const float* x      = (const float*)d_in[0];
    const float* qkv_w  = (const float*)d_in[1];
    const float* qkv_b  = (const float*)d_in[2];
    const float* proj_w = (const float*)d_in[3];
    const float* proj_b = (const float*)d_in[4];
    float* out = (float*)d_out;

    unsigned short* base16 = (unsigned short*)d_ws;
    unsigned short* vT16   = base16;                      // 25165824 u16
    unsigned short* attbuf = base16 + 25165824;           // 25165824 u16
    float* qg = (float*)(base16 + 50331648);              // 393216 f32
    float* kg = qg + 393216;                              // 393216 f32
    unsigned short* Wh = (unsigned short*)(kg + 393216);  // 110592 u16
    unsigned short* Wl = Wh + 110592;                     // 73728 u16
    unsigned short* Wp = Wl + 73728;                      // 36864 u16

    wsplit_kernel<<<432, 256, 0, stream>>>(qkv_w, Wh, Wl);
    wproj_kernel<<<144, 256, 0, stream>>>(proj_w, Wp);
    qkv_fused_kernel<<<2048, 256, 0, stream>>>(x, Wh, Wl, qkv_b, vT16, qg, kg);
    attn_mfma_kernel<<<1536, 256, 0, stream>>>(vT16, qg, kg, attbuf);
    proj_mfma_kernel<<<2048, 256, 0, stream>>>(attbuf, Wp, proj_b, out);
}